// Round 7
// baseline (595.525 us; speedup 1.0000x reference)
//
#include <hip/hip_runtime.h>
#include <stdint.h>

typedef __bf16 bf16;
typedef __bf16 bf16x8 __attribute__((ext_vector_type(8)));
typedef float  f32x4  __attribute__((ext_vector_type(4)));

#define NSEQ 4096
#define NROWS 16384
#define CHUNK 32
#define NCHUNKS_B 128
#define SEGLEN 16
#define NSEG 8
#define NBLK 512

__device__ __forceinline__ float bf2f(uint16_t u){
    uint32_t w = ((uint32_t)u) << 16;
    return __builtin_bit_cast(float, w);
}
__device__ __forceinline__ uint32_t pack2(float a, float b){
    uint16_t ua = __builtin_bit_cast(uint16_t, (bf16)a);
    uint16_t ub = __builtin_bit_cast(uint16_t, (bf16)b);
    return ((uint32_t)ub << 16) | (uint32_t)ua;
}
__device__ __forceinline__ uint4 cvt8(const float* p){
    float4 lo = *(const float4*)p;
    float4 hi = *(const float4*)(p + 4);
    uint4 r;
    r.x = pack2(lo.x, lo.y); r.y = pack2(lo.z, lo.w);
    r.z = pack2(hi.x, hi.y); r.w = pack2(hi.z, hi.w);
    return r;
}
__device__ __forceinline__ float rd_any(const void* p, long idx, int f){
    return f ? ((const float*)p)[idx] : (float)((const bf16*)p)[idx];
}
// async global->LDS, 16B/lane; lds dest wave-uniform (dest = l + lane*16)
__device__ __forceinline__ void cp16(const void* g, void* l){
    __builtin_amdgcn_global_load_lds((const __attribute__((address_space(1))) void*)g,
                                     (__attribute__((address_space(3))) void*)l,
                                     16, 0, 0);
}

// ---- software grid barrier (device-scope, no cooperative API) ----
// bar[0]=arrive count (monotone), bar[1]=sense epoch. k = barrier index (0-based).
__device__ __forceinline__ void gbar(unsigned* bar, int k){
    __syncthreads();
    if (threadIdx.x == 0){
        unsigned epoch = __hip_atomic_load(&bar[1], __ATOMIC_ACQUIRE, __HIP_MEMORY_SCOPE_AGENT);
        unsigned my = __hip_atomic_fetch_add(&bar[0], 1u, __ATOMIC_ACQ_REL, __HIP_MEMORY_SCOPE_AGENT);
        if (my == (unsigned)(NBLK*(k+1)) - 1u){
            __hip_atomic_fetch_add(&bar[1], 1u, __ATOMIC_ACQ_REL, __HIP_MEMORY_SCOPE_AGENT);
        } else {
            long spins = 0;
            while (__hip_atomic_load(&bar[1], __ATOMIC_ACQUIRE, __HIP_MEMORY_SCOPE_AGENT) == epoch){
                __builtin_amdgcn_s_sleep(2);
                if (++spins > 200000000L) break;   // safety: clean-fail, not hang
            }
        }
    }
    __syncthreads();
}

__global__ __launch_bounds__(64) void init_bar(unsigned* bar){
    if (threadIdx.x < 2) bar[threadIdx.x] = 0u;
}

struct KArgs {
    const void* x;  const void* Wi; const void* We; const void* Ws;
    const void* op; const void* g;  const void* b;  const void* Wo;
    bf16* Wt_i; bf16* Wt_o; bf16* iy; float* e; float* s;
    float* o_t; float* oL_t; float* lsL_t; float* oL16_t;
    float* Ams; float* Tbuf; bf16* Wt_es; float* g_c; float* b_c;
    unsigned* bar;
    void* out;
};

// ---- GEMM phase: C(16384x512) = A * Bt^T; optional fused e/s projection ----
__device__ __forceinline__ void gemm_phase(const void* Avoid, const bf16* Bt, void* Cvoid,
                                           int fa, int fc, char* smem, int bid, int tid,
                                           const bf16* Wt_es, float* e, float* s, int do_es){
    bf16* As = (bf16*)smem;            // 128x32 = 8192 B
    bf16* Bs = (bf16*)(smem + 8192);   // 8192 B
    const int lane = tid & 63;
    const int wave = tid >> 6;
    const int mtile = bid >> 2;        // 512 blocks = 128 mtiles x 4 ntiles
    const int ntile = bid & 3;
    const int m0 = mtile << 7, n0 = ntile << 7;
    const int wr = (wave >> 1) << 6;
    const int wc = (wave & 1) << 6;
    const int lrow = lane & 15;
    const int quad = lane >> 4;
    const int es_on = do_es && (ntile == 0);

    f32x4 acc[4][4] = {};
    f32x4 esa[4] = {};

    const int sr = tid >> 2;
    const int sk = (tid & 3) << 3;
    const bf16*  Ag  = (const bf16*) Avoid + (long)(m0 + sr)*512 + sk;
    const float* Agf = (const float*)Avoid + (long)(m0 + sr)*512 + sk;
    const bf16*  Bg  = Bt + (long)(n0 + sr)*512 + sk;

    #pragma unroll
    for (int k0 = 0; k0 < 512; k0 += 32){
        uint4 a0, a1;
        if (fa){
            a0 = cvt8(Agf + k0);
            a1 = cvt8(Agf + (long)64*512 + k0);
        }
        if (k0) __syncthreads();
        if (fa){
            *(uint4*)&As[tid*8]        = a0;
            *(uint4*)&As[2048 + tid*8] = a1;
        } else {
            cp16(Ag + k0,               &As[(size_t)wave*512]);
            cp16(Ag + (long)64*512 + k0,&As[2048 + (size_t)wave*512]);
        }
        cp16(Bg + k0,               &Bs[(size_t)wave*512]);
        cp16(Bg + (long)64*512 + k0,&Bs[2048 + (size_t)wave*512]);
        __syncthreads();

        bf16x8 af[4], bfr[4];
        #pragma unroll
        for (int i = 0; i < 4; ++i)
            af[i]  = *(const bf16x8*)&As[(wr + i*16 + lrow)*32 + quad*8];
        #pragma unroll
        for (int j = 0; j < 4; ++j)
            bfr[j] = *(const bf16x8*)&Bs[(wc + j*16 + lrow)*32 + quad*8];
        if (es_on){
            bf16x8 eb = *(const bf16x8*)&Wt_es[lrow*512 + k0 + quad*8];
            #pragma unroll
            for (int i = 0; i < 4; ++i)
                esa[i] = __builtin_amdgcn_mfma_f32_16x16x32_bf16(af[i], eb, esa[i], 0, 0, 0);
        }
        #pragma unroll
        for (int i = 0; i < 4; ++i)
            #pragma unroll
            for (int j = 0; j < 4; ++j)
                acc[i][j] = __builtin_amdgcn_mfma_f32_16x16x32_bf16(af[i], bfr[j], acc[i][j], 0, 0, 0);
    }

    if (es_on){
        float* outp = (lrow < 8) ? e : s;
        int col = lrow & 7;
        #pragma unroll
        for (int i = 0; i < 4; ++i)
            #pragma unroll
            for (int r = 0; r < 4; ++r)
                outp[(long)(m0 + wr + i*16 + quad*4 + r)*8 + col] = esa[i][r];
    }

    // C/D layout: col = lane&15, row = quad*4 + reg
    if (fc){
        float* Cf = (float*)Cvoid;
        #pragma unroll
        for (int i = 0; i < 4; ++i){
            int gr = m0 + wr + i*16 + quad*4;
            #pragma unroll
            for (int j = 0; j < 4; ++j){
                int gc = n0 + wc + j*16 + lrow;
                #pragma unroll
                for (int r = 0; r < 4; ++r)
                    Cf[(long)(gr + r)*512 + gc] = acc[i][j][r];
            }
        }
    } else {
        // repack through LDS in two 64-row halves -> coalesced 16B stores
        bf16* Ct = (bf16*)smem;            // 64 x 136 = 17408 B
        bf16* Cb = (bf16*)Cvoid;
        #pragma unroll
        for (int h = 0; h < 2; ++h){
            __syncthreads();               // prior LDS use done
            if (wr == h*64){
                #pragma unroll
                for (int i = 0; i < 4; ++i){
                    int lr = i*16 + quad*4;
                    #pragma unroll
                    for (int j = 0; j < 4; ++j){
                        int lc = wc + j*16 + lrow;
                        #pragma unroll
                        for (int r = 0; r < 4; ++r)
                            Ct[(lr + r)*136 + lc] = (bf16)acc[i][j][r];
                    }
                }
            }
            __syncthreads();
            int c8 = (tid & 15) * 8;
            int rb = tid >> 4;
            #pragma unroll
            for (int e2 = 0; e2 < 4; ++e2){
                int row = e2*16 + rb;
                uint4 v = *(const uint4*)&Ct[row*136 + c8];
                *(uint4*)&Cb[(long)(m0 + h*64 + row)*512 + n0 + c8] = v;
            }
        }
    }
}

__global__ __launch_bounds__(256, 2) void mega(KArgs A){
    __shared__ __align__(16) char smem[17408];
    const int tid = threadIdx.x;
    const int bid = blockIdx.x;
    const int lane = tid & 63;
    const int wave = tid >> 6;

    // ---- dtype flag: every block computes it (uniform, deterministic) ----
    int f;
    {
        int* cnt = (int*)smem;
        const uint32_t* xw = (const uint32_t*)A.x;
        int c = 0;
        #pragma unroll
        for (int j = 0; j < 4; ++j){
            uint32_t w = xw[tid*4 + j];
            uint32_t ee = (w >> 7) & 0xFF;
            c += (ee >= 110 && ee <= 140) ? 1 : 0;
        }
        cnt[tid] = c; __syncthreads();
        for (int s2 = 128; s2; s2 >>= 1){
            if (tid < s2) cnt[tid] += cnt[tid + s2];
            __syncthreads();
        }
        f = (cnt[0] < 512) ? 1 : 0;
        __syncthreads();
    }

    // ---- ph0: weight transposes + decay tables + small conversions ----
    if (bid < 128){
        bf16 (*T)[65] = (bf16(*)[65])smem;     // 8320 B
        int mat = bid >> 6, t = bid & 63;
        int k0 = (t >> 3)*64, n0 = (t & 7)*64;
        const void* in = mat ? A.Wo : A.Wi;
        bf16* outp = mat ? A.Wt_o : A.Wt_i;
        #pragma unroll
        for (int e2 = 0; e2 < 16; ++e2){
            int idx = e2*256 + tid;
            int r = idx >> 6, c = idx & 63;
            T[c][r] = (bf16)rd_any(in, (long)(k0 + r)*512 + n0 + c, f);
        }
        __syncthreads();
        #pragma unroll
        for (int e2 = 0; e2 < 16; ++e2){
            int idx = e2*256 + tid;
            int rn = idx >> 6, ck = idx & 63;
            outp[(long)(n0 + rn)*512 + k0 + ck] = T[rn][ck];
        }
    } else if (bid < 144){
        int i = (bid - 128)*256 + tid;         // 0..4095
        float xv = rd_any(A.op, i, f);
        float ls = (xv < 0.f) ? (xv - log1pf(expf(xv))) : (0.f - log1pf(expf(-xv)));
        A.o_t[i]    = expf(ls * (1.0f/16.0f)); // o = sigmoid^(1/16)
        A.oL_t[i]   = expf(ls * 2.0f);         // o^32
        A.lsL_t[i]  = ls * 2.0f;               // log(o^32)
        A.oL16_t[i] = expf(ls * 32.0f);        // o^512
    } else if (bid == 144){
        for (int i = tid; i < 8192; i += 256){
            int n = i >> 9, k = i & 511;
            float v = (n < 8) ? rd_any(A.We, (long)k*8 + n, f)
                              : rd_any(A.Ws, (long)k*8 + (n-8), f);
            A.Wt_es[i] = (bf16)v;
        }
    } else if (bid == 145){
        for (int i = tid; i < 512; i += 256){
            A.g_c[i] = rd_any(A.g, i, f);
            A.b_c[i] = rd_any(A.b, i, f);
        }
    }
    gbar(A.bar, 0);

    // ---- ph1: gemm1 (i = x @ W_i) with fused e/s projection ----
    gemm_phase(A.x, A.Wt_i, A.iy, f, 0, smem, bid, tid, A.Wt_es, A.e, A.s, 1);
    gbar(A.bar, 1);

    // ---- ph2: passA — per-chunk local state from zero ----
    {
        int c = bid, b = c >> 7, t0 = (c & 127)*CHUNK;
        float* eS = (float*)smem;
        eS[tid] = A.e[((long)(b*NSEQ + t0))*8 + tid];
        __syncthreads();
        int d0 = tid*2;
        float o0[8], o1[8], mm0[8], mm1[8];
        #pragma unroll
        for (int k = 0; k < 8; ++k){
            o0[k] = A.o_t[k*512 + d0]; o1[k] = A.o_t[k*512 + d0 + 1];
            mm0[k] = 0.f; mm1[k] = 0.f;
        }
        const bf16* ip = A.iy + (long)(b*NSEQ + t0)*512 + d0;
        #pragma unroll 4
        for (int t = 0; t < CHUNK; ++t){
            uint32_t iv = *(const uint32_t*)(ip + (long)t*512);
            float i0 = bf2f((uint16_t)iv), i1 = bf2f((uint16_t)(iv >> 16));
            #pragma unroll
            for (int k = 0; k < 8; ++k){
                float ek = eS[t*8 + k];
                mm0[k] = o0[k]*mm0[k] + ek*i0;
                mm1[k] = o1[k]*mm1[k] + ek*i1;
            }
        }
        float* Ac = A.Ams + (long)c*4096;
        #pragma unroll
        for (int k = 0; k < 8; ++k){
            float2 v; v.x = mm0[k]; v.y = mm1[k];
            *(float2*)&Ac[k*512 + d0] = v;
        }
    }
    gbar(A.bar, 2);

    // ---- ph3: passB1 — register scan within 16-chunk segment + totals ----
    {
        int bs = bid >> 4;                     // 0..31
        int b = bs >> 3, seg = bs & 7;
        int idx = (bid & 15)*256 + tid;        // 0..4095
        float oL = A.oL_t[idx];
        float* Mb = A.Ams + ((long)b*NCHUNKS_B + seg*SEGLEN)*4096 + idx;
        float a[SEGLEN];
        #pragma unroll
        for (int cc = 0; cc < SEGLEN; ++cc)
            a[cc] = Mb[(long)cc*4096];
        float m = 0.f;
        #pragma unroll
        for (int cc = 0; cc < SEGLEN; ++cc){
            Mb[(long)cc*4096] = m;
            m = oL*m + a[cc];
        }
        A.Tbuf[(long)bs*4096 + idx] = m;
    }
    gbar(A.bar, 3);

    // ---- ph4: passB2 — scan segment totals (64 active blocks) ----
    if (bid < 64){
        int b = bid >> 4;
        int idx = (bid & 15)*256 + tid;
        float oL16 = A.oL16_t[idx];
        float t[NSEG];
        #pragma unroll
        for (int s2 = 0; s2 < NSEG; ++s2)
            t[s2] = A.Tbuf[((long)b*NSEG + s2)*4096 + idx];
        float m = 0.f;
        #pragma unroll
        for (int s2 = 0; s2 < NSEG; ++s2){
            A.Tbuf[((long)b*NSEG + s2)*4096 + idx] = m;
            m = oL16*m + t[s2];
        }
    }
    gbar(A.bar, 4);

    // ---- ph5: passC + fused LayerNorm — replay chunk, y overwrites i ----
    {
        int c = bid, b = c >> 7, cI = c & 127;
        int seg = cI >> 4;
        float fj = (float)(cI & 15);
        int t0 = cI*CHUNK;
        float* eS = (float*)smem;
        float* sS = eS + 256;
        float* red = (float*)(smem + 2048);    // [par*8 + which*4 + wave]
        eS[tid] = A.e[((long)(b*NSEQ + t0))*8 + tid];
        sS[tid] = A.s[((long)(b*NSEQ + t0))*8 + tid];
        __syncthreads();
        int d0 = tid*2;
        float o0[8], o1[8], mm0[8], mm1[8];
        const float* P0 = A.Ams + (long)c*4096;
        const float* Ms = A.Tbuf + ((long)b*NSEG + seg)*4096;
        #pragma unroll
        for (int k = 0; k < 8; ++k){
            int i0 = k*512 + d0;
            o0[k] = A.o_t[i0]; o1[k] = A.o_t[i0 + 1];
            mm0[k] = P0[i0]   + __expf(A.lsL_t[i0]  *fj)*Ms[i0];
            mm1[k] = P0[i0+1] + __expf(A.lsL_t[i0+1]*fj)*Ms[i0+1];
        }
        float gg0 = A.g_c[d0], gg1 = A.g_c[d0+1];
        float bb0 = A.b_c[d0], bb1 = A.b_c[d0+1];
        bf16* ip = A.iy + (long)(b*NSEQ + t0)*512 + d0;
        for (int t = 0; t < CHUNK; ++t){
            uint32_t iv = *(const uint32_t*)(ip + (long)t*512);
            float i0 = bf2f((uint16_t)iv), i1 = bf2f((uint16_t)(iv >> 16));
            float y0 = 0.f, y1 = 0.f;
            #pragma unroll
            for (int k = 0; k < 8; ++k){
                float ek = eS[t*8 + k], sk = sS[t*8 + k];
                mm0[k] = o0[k]*mm0[k] + ek*i0;
                mm1[k] = o1[k]*mm1[k] + ek*i1;
                y0 += sk*mm0[k];
                y1 += sk*mm1[k];
            }
            float s = y0 + y1, s2 = y0*y0 + y1*y1;
            #pragma unroll
            for (int off = 32; off >= 1; off >>= 1){
                s  += __shfl_xor(s, off);
                s2 += __shfl_xor(s2, off);
            }
            int par = t & 1;
            if (lane == 0){ red[par*8 + wave] = s; red[par*8 + 4 + wave] = s2; }
            __syncthreads();
            float S  = red[par*8 + 0] + red[par*8 + 1] + red[par*8 + 2] + red[par*8 + 3];
            float S2 = red[par*8 + 4] + red[par*8 + 5] + red[par*8 + 6] + red[par*8 + 7];
            float mu  = S * (1.f/512.f);
            float var = S2 * (1.f/512.f) - mu*mu;
            float r = rsqrtf(var + 1e-5f);
            float z0 = (y0 - mu)*r*gg0 + bb0;
            float z1 = (y1 - mu)*r*gg1 + bb1;
            *(uint32_t*)(ip + (long)t*512) = pack2(z0, z1);
        }
    }
    gbar(A.bar, 5);

    // ---- ph6: gemm2 (out = y @ W_out) ----
    gemm_phase(A.iy, A.Wt_o, A.out, 0, f, smem, bid, tid, nullptr, nullptr, nullptr, 0);
}

extern "C" void kernel_launch(void* const* d_in, const int* in_sizes, int n_in,
                              void* d_out, int out_size, void* d_ws, size_t ws_size,
                              hipStream_t stream){
    char* ws = (char*)d_ws;
    KArgs a;
    a.x  = d_in[0]; a.Wi = d_in[1]; a.We = d_in[2]; a.Ws = d_in[3];
    a.op = d_in[4]; a.g  = d_in[5]; a.b  = d_in[6]; a.Wo = d_in[7];
    a.Wt_i   = (bf16*) (ws + 0);          // 512 KB (dead after ph1)
    a.Tbuf   = (float*)(ws + 0);          // aliased over Wt_i (ph3+)
    a.Wt_o   = (bf16*) (ws + 524288);     // 512 KB
    a.iy     = (bf16*) (ws + 1048576);    // 16 MB (i, then y in-place)
    a.e      = (float*)(ws + 17825792);   // 512 KB
    a.s      = (float*)(ws + 18350080);   // 512 KB
    a.o_t    = (float*)(ws + 18874368);   // 16 KB
    a.oL_t   = (float*)(ws + 18890752);   // 16 KB
    a.lsL_t  = (float*)(ws + 18907136);   // 16 KB
    a.oL16_t = (float*)(ws + 18923520);   // 16 KB
    a.Ams    = (float*)(ws + 18939904);   // 8 MB
    a.Wt_es  = (bf16*) (ws + 27328512);   // 16 KB
    a.g_c    = (float*)(ws + 27344896);   // 2 KB
    a.b_c    = (float*)(ws + 27346944);   // 2 KB
    a.bar    = (unsigned*)(ws + 27348992);// 8 B barrier state
    a.out    = d_out;

    init_bar<<<1, 64, 0, stream>>>(a.bar);
    mega<<<NBLK, 256, 0, stream>>>(a);
}